// Round 2
// baseline (308.568 us; speedup 1.0000x reference)
//
#include <hip/hip_runtime.h>
#include <hip/hip_fp16.h>
#include <cstdint>
#include <cstddef>

#define BB 4
#define CC 256
#define NN 4096
#define EPS_NORM 2.220446049250313e-16f
#define EPS_MIN 1e-5f

typedef __attribute__((ext_vector_type(8))) short short8;
typedef __attribute__((ext_vector_type(4))) float floatx4;

__device__ __forceinline__ unsigned fmap(float f) {
    unsigned u = __float_as_uint(f);
    return (u & 0x80000000u) ? ~u : (u | 0x80000000u);
}
__device__ __forceinline__ float funmap(unsigned u) {
    return (u & 0x80000000u) ? __uint_as_float(u ^ 0x80000000u) : __uint_as_float(~u);
}
__device__ __forceinline__ unsigned short f2bf(float f) {
    unsigned u = __float_as_uint(f);
    u += 0x7FFFu + ((u >> 16) & 1u);   // RNE
    return (unsigned short)(u >> 16);
}
__device__ __forceinline__ void async_cp16(const void* g, void* l) {
    __builtin_amdgcn_global_load_lds(
        (const __attribute__((address_space(1))) unsigned int*)g,
        (__attribute__((address_space(3))) unsigned int*)l, 16, 0, 0);
}

// ---- K1: per-channel spatial mean of Y (float4) ---------------------------
__global__ void kmean(const float* __restrict__ Y, float* __restrict__ ymean) {
    int bc = blockIdx.x;  // b*CC + c
    const float4* p = (const float4*)(Y + (size_t)bc * NN);
    float s = 0.f;
    for (int k = threadIdx.x; k < NN / 4; k += 256) {
        float4 v = p[k];
        s += (v.x + v.y) + (v.z + v.w);
    }
    __shared__ float red[256];
    red[threadIdx.x] = s; __syncthreads();
    for (int st = 128; st > 0; st >>= 1) {
        if (threadIdx.x < st) red[threadIdx.x] += red[threadIdx.x + st];
        __syncthreads();
    }
    if (threadIdx.x == 0) ymean[bc] = red[0] * (1.0f / NN);
}

// ------- K2: fused norm + normalize + transpose -> bf16 [B,N,C] -------------
__global__ __launch_bounds__(256)
void kfuse(const float* __restrict__ X, const float* __restrict__ Y,
           const float* __restrict__ ymean,
           unsigned short* __restrict__ XnT, unsigned short* __restrict__ YnT) {
    int b = blockIdx.y >> 1, which = blockIdx.y & 1;
    const float* src = which ? Y : X;
    unsigned short* dst = which ? YnT : XnT;
    int n0 = blockIdx.x * 64;
    int tx = threadIdx.x & 63, ty = threadIdx.x >> 6;
    __shared__ float mean_s[CC];
    __shared__ float red[4][64];
    __shared__ float invn[64];
    __shared__ float tile[64][65];
    mean_s[threadIdx.x] = ymean[b * CC + threadIdx.x];
    __syncthreads();
    float vreg[64];
    float s = 0.f;
    #pragma unroll
    for (int k = 0; k < 64; ++k) {
        int c = ty + 4 * k;
        float v = src[(((size_t)b * CC + c) << 12) + n0 + tx] - mean_s[c];
        vreg[k] = v;
        s += v * v;
    }
    red[ty][tx] = s; __syncthreads();
    if (ty == 0) {
        float t = red[0][tx] + red[1][tx] + red[2][tx] + red[3][tx];
        invn[tx] = 1.0f / (sqrtf(t) + EPS_NORM);
    }
    __syncthreads();
    float inv = invn[tx];
    for (int cb = 0; cb < 4; ++cb) {
        if (cb) __syncthreads();
        #pragma unroll
        for (int kk = 0; kk < 16; ++kk) {
            tile[4 * kk + ty][tx] = vreg[cb * 16 + kk] * inv;
        }
        __syncthreads();
        #pragma unroll
        for (int it = 0; it < 16; ++it) {
            int nl = ty + it * 4;
            dst[((size_t)(b * NN + n0 + nl)) * CC + cb * 64 + tx] = f2bf(tile[tx][nl]);
        }
    }
}

// ---------------- init accumulators -----------------------------------------
__global__ void kinit(unsigned* __restrict__ rowminU, float* __restrict__ rowsum,
                      unsigned* __restrict__ colmaxU) {
    int idx = blockIdx.x * 256 + threadIdx.x;
    rowminU[idx] = 0xFF800000u;   // fmap(+inf)
    rowsum[idx] = 0.f;
    colmaxU[idx] = 0x007FFFFFu;   // fmap(-inf)
}

// -------- GEMM core: s = A.B^T, XOR-swizzled async-staged LDS ---------------
// No S materialization. 3 recompute passes with fused reductions:
// MODE 1: atomic row-min of d.  MODE 2: atomic row-sum of exp (alpha inline).
// MODE 3: col-max of (beta - alpha*d) (alpha,beta inline).
// Grid is 1-D 4096 blocks, XCD-partitioned: xcd = bid&7 owns batch (xcd>>1)
// and i-panel half (xcd&1): working set = 1 MB XnT-half + 2 MB YnT < 4 MB L2.
template <int MODE>
__global__ __launch_bounds__(256, 4)
void kgemm3(const unsigned short* __restrict__ Aptr, const unsigned short* __restrict__ Bptr,
            unsigned* __restrict__ rowminU, float* __restrict__ rowsum,
            unsigned* __restrict__ colmaxU) {
    const int bid = blockIdx.x;
    const int xcd = bid & 7, q = bid >> 3;
    const int b = xcd >> 1;
    const int by = (xcd & 1) * 16 + (q >> 5);
    const int bx = q & 31;
    const int i0 = by * 128, j0 = bx * 128;
    const int tid = threadIdx.x, lane = tid & 63, wave = tid >> 6;
    const int wm = wave >> 1, wn = wave & 1, l15 = lane & 15, quad = lane >> 4;
    __shared__ unsigned short smem[16384];   // A 128x64 | B 128x64 staging
    unsigned short* As = smem;
    unsigned short* Bs = smem + 128 * 64;
    floatx4 acc[4][4];
    #pragma unroll
    for (int ms = 0; ms < 4; ++ms)
        #pragma unroll
        for (int ns = 0; ns < 4; ++ns) acc[ms][ns] = (floatx4){0.f, 0.f, 0.f, 0.f};

    const unsigned short* gA = Aptr + (size_t)b * NN * CC + (size_t)i0 * CC;
    const unsigned short* gB = Bptr + (size_t)b * NN * CC + (size_t)j0 * CC;
    int rl = lane >> 3, pos = lane & 7;
    int cb = pos ^ (rl & 7);
    const unsigned short* gAl = gA + (size_t)(wave * 32 + rl) * CC + cb * 8;
    const unsigned short* gBl = gB + (size_t)(wave * 32 + rl) * CC + cb * 8;
    unsigned short* lA = As + (wave * 32) * 64;
    unsigned short* lB = Bs + (wave * 32) * 64;

    for (int kc = 0; kc < CC; kc += 64) {
        #pragma unroll
        for (int seg = 0; seg < 4; ++seg) {
            async_cp16(gAl + (size_t)seg * 8 * CC + kc, lA + seg * 8 * 64);
            async_cp16(gBl + (size_t)seg * 8 * CC + kc, lB + seg * 8 * 64);
        }
        __syncthreads();
        #pragma unroll
        for (int kk = 0; kk < 64; kk += 32) {
            short8 af[4], bf[4];
            int sw = (quad + (kk >> 3)) ^ (l15 & 7);
            #pragma unroll
            for (int s = 0; s < 4; ++s) {
                af[s] = *(const short8*)&As[(wm * 64 + s * 16 + l15) * 64 + (sw << 3)];
                bf[s] = *(const short8*)&Bs[(wn * 64 + s * 16 + l15) * 64 + (sw << 3)];
            }
            #pragma unroll
            for (int ms = 0; ms < 4; ++ms)
                #pragma unroll
                for (int ns = 0; ns < 4; ++ns)
                    acc[ms][ns] = __builtin_amdgcn_mfma_f32_16x16x32_bf16(af[ms], bf[ns], acc[ms][ns], 0, 0, 0);
        }
        __syncthreads();
    }

    const int ibase = i0 + wm * 64, jbase = j0 + wn * 64;
    if (MODE == 1) {
        #pragma unroll
        for (int ms = 0; ms < 4; ++ms)
            #pragma unroll
            for (int r = 0; r < 4; ++r) {
                float m = 1e30f;
                #pragma unroll
                for (int ns = 0; ns < 4; ++ns) m = fminf(m, 1.0f - acc[ms][ns][r]);
                m = fminf(m, __shfl_xor(m, 1)); m = fminf(m, __shfl_xor(m, 2));
                m = fminf(m, __shfl_xor(m, 4)); m = fminf(m, __shfl_xor(m, 8));
                if (l15 == 0) {
                    int i = ibase + ms * 16 + quad * 4 + r;
                    atomicMin(&rowminU[b * NN + i], fmap(m));
                }
            }
    } else if (MODE == 2) {
        #pragma unroll
        for (int ms = 0; ms < 4; ++ms)
            #pragma unroll
            for (int r = 0; r < 4; ++r) {
                int i = ibase + ms * 16 + quad * 4 + r;
                float al = 10.0f / (funmap(rowminU[b * NN + i]) + EPS_MIN);
                float s = 0.f;
                #pragma unroll
                for (int ns = 0; ns < 4; ++ns) s += __expf(10.0f - al * (1.0f - acc[ms][ns][r]));
                s += __shfl_xor(s, 1); s += __shfl_xor(s, 2);
                s += __shfl_xor(s, 4); s += __shfl_xor(s, 8);
                if (l15 == 0) atomicAdd(&rowsum[b * NN + i], s);
            }
    } else {  // MODE 3
        float cm[4] = {-1e30f, -1e30f, -1e30f, -1e30f};
        #pragma unroll
        for (int ms = 0; ms < 4; ++ms)
            #pragma unroll
            for (int r = 0; r < 4; ++r) {
                int i = ibase + ms * 16 + quad * 4 + r;
                float al = 10.0f / (funmap(rowminU[b * NN + i]) + EPS_MIN);
                float bl = 10.0f - __logf(rowsum[b * NN + i]);
                #pragma unroll
                for (int ns = 0; ns < 4; ++ns) {
                    float t = bl - al * (1.0f - acc[ms][ns][r]);
                    cm[ns] = fmaxf(cm[ns], t);
                }
            }
        #pragma unroll
        for (int ns = 0; ns < 4; ++ns) {
            float v = cm[ns];
            v = fmaxf(v, __shfl_xor(v, 16)); v = fmaxf(v, __shfl_xor(v, 32));
            if (quad == 0) {
                int j = jbase + ns * 16 + l15;
                atomicMax(&colmaxU[b * NN + j], fmap(v));
            }
        }
    }
}

// ---- final: out[b] = log(N) - log(sum_j exp(colmax_j)) ---------------------
__global__ void kfinalR(const unsigned* __restrict__ colmaxU, float* __restrict__ out) {
    int b = blockIdx.x;
    float s = 0.f;
    for (int j = threadIdx.x; j < NN; j += 256) s += __expf(funmap(colmaxU[b * NN + j]));
    __shared__ float red[256];
    red[threadIdx.x] = s; __syncthreads();
    for (int st = 128; st > 0; st >>= 1) {
        if (threadIdx.x < st) red[threadIdx.x] += red[threadIdx.x + st];
        __syncthreads();
    }
    if (threadIdx.x == 0) out[b] = logf((float)NN) - logf(red[0]);
}

extern "C" void kernel_launch(void* const* d_in, const int* in_sizes, int n_in,
                              void* d_out, int out_size, void* d_ws, size_t ws_size,
                              hipStream_t stream) {
    const float* X = (const float*)d_in[0];
    const float* Y = (const float*)d_in[1];
    float* out = (float*)d_out;

    char* w = (char*)d_ws;
    float* ymean        = (float*)(w + 0);                 //   4 KiB
    unsigned* rowminU   = (unsigned*)(w + 4096);           //  64 KiB
    float* rowsum       = (float*)(w + 69632);             //  64 KiB
    unsigned* colmaxU   = (unsigned*)(w + 135168);         //  64 KiB
    unsigned short* XnT = (unsigned short*)(w + 200704);   //   8 MiB
    unsigned short* YnT = (unsigned short*)(w + 8589312);  //   8 MiB  (total ~16.2 MiB)

    kmean<<<dim3(BB * CC), 256, 0, stream>>>(Y, ymean);
    kfuse<<<dim3(NN / 64, BB * 2), 256, 0, stream>>>(X, Y, ymean, XnT, YnT);
    kinit<<<dim3(BB * NN / 256), 256, 0, stream>>>(rowminU, rowsum, colmaxU);

    dim3 ggrid(8 * 16 * 32);   // 4096 blocks, XCD-partitioned decode in-kernel
    kgemm3<1><<<ggrid, 256, 0, stream>>>(XnT, YnT, rowminU, rowsum, colmaxU);
    kgemm3<2><<<ggrid, 256, 0, stream>>>(XnT, YnT, rowminU, rowsum, colmaxU);
    kgemm3<3><<<ggrid, 256, 0, stream>>>(XnT, YnT, rowminU, rowsum, colmaxU);

    kfinalR<<<dim3(BB), 256, 0, stream>>>(colmaxU, out);
}

// Round 3
// 250.369 us; speedup vs baseline: 1.2325x; 1.2325x over previous
//
#include <hip/hip_runtime.h>
#include <hip/hip_fp16.h>
#include <cstdint>
#include <cstddef>

#define BB 4
#define CC 256
#define NN 4096
#define EPS_NORM 2.220446049250313e-16f
#define EPS_MIN 1e-5f

typedef __attribute__((ext_vector_type(8))) short short8;
typedef __attribute__((ext_vector_type(4))) float floatx4;

__device__ __forceinline__ unsigned short f2bf(float f) {
    unsigned u = __float_as_uint(f);
    u += 0x7FFFu + ((u >> 16) & 1u);   // RNE
    return (unsigned short)(u >> 16);
}
__device__ __forceinline__ void async_cp16(const void* g, void* l) {
    __builtin_amdgcn_global_load_lds(
        (const __attribute__((address_space(1))) unsigned int*)g,
        (__attribute__((address_space(3))) unsigned int*)l, 16, 0, 0);
}

// ---- K1: per-channel spatial mean of Y (float4); also zero sums ------------
__global__ void kmean(const float* __restrict__ Y, float* __restrict__ ymean,
                      float* __restrict__ sums) {
    if (blockIdx.x == 0 && threadIdx.x < BB) sums[threadIdx.x] = 0.f;
    int bc = blockIdx.x;  // b*CC + c
    const float4* p = (const float4*)(Y + (size_t)bc * NN);
    float s = 0.f;
    for (int k = threadIdx.x; k < NN / 4; k += 256) {
        float4 v = p[k];
        s += (v.x + v.y) + (v.z + v.w);
    }
    __shared__ float red[256];
    red[threadIdx.x] = s; __syncthreads();
    for (int st = 128; st > 0; st >>= 1) {
        if (threadIdx.x < st) red[threadIdx.x] += red[threadIdx.x + st];
        __syncthreads();
    }
    if (threadIdx.x == 0) ymean[bc] = red[0] * (1.0f / NN);
}

// ------- K2: fused norm + normalize + transpose -> bf16 [B,N,C] -------------
__global__ __launch_bounds__(256)
void kfuse(const float* __restrict__ X, const float* __restrict__ Y,
           const float* __restrict__ ymean,
           unsigned short* __restrict__ XnT, unsigned short* __restrict__ YnT) {
    int b = blockIdx.y >> 1, which = blockIdx.y & 1;
    const float* src = which ? Y : X;
    unsigned short* dst = which ? YnT : XnT;
    int n0 = blockIdx.x * 64;
    int tx = threadIdx.x & 63, ty = threadIdx.x >> 6;
    __shared__ float mean_s[CC];
    __shared__ float red[4][64];
    __shared__ float invn[64];
    __shared__ float tile[64][65];
    mean_s[threadIdx.x] = ymean[b * CC + threadIdx.x];
    __syncthreads();
    float vreg[64];
    float s = 0.f;
    #pragma unroll
    for (int k = 0; k < 64; ++k) {
        int c = ty + 4 * k;
        float v = src[(((size_t)b * CC + c) << 12) + n0 + tx] - mean_s[c];
        vreg[k] = v;
        s += v * v;
    }
    red[ty][tx] = s; __syncthreads();
    if (ty == 0) {
        float t = red[0][tx] + red[1][tx] + red[2][tx] + red[3][tx];
        invn[tx] = 1.0f / (sqrtf(t) + EPS_NORM);
    }
    __syncthreads();
    float inv = invn[tx];
    for (int cb = 0; cb < 4; ++cb) {
        if (cb) __syncthreads();
        #pragma unroll
        for (int kk = 0; kk < 16; ++kk) {
            tile[4 * kk + ty][tx] = vreg[cb * 16 + kk] * inv;
        }
        __syncthreads();
        #pragma unroll
        for (int it = 0; it < 16; ++it) {
            int nl = ty + it * 4;
            dst[((size_t)(b * NN + n0 + nl)) * CC + cb * 64 + tx] = f2bf(tile[tx][nl]);
        }
    }
}

__device__ __forceinline__ void stage_tile(const unsigned short* gA_, const unsigned short* gB_,
                                           unsigned short* lA_, unsigned short* lB_) {
    #pragma unroll
    for (int seg = 0; seg < 4; ++seg) {
        async_cp16(gA_ + (size_t)seg * 8 * CC, lA_ + seg * 8 * 64);
        async_cp16(gB_ + (size_t)seg * 8 * CC, lB_ + seg * 8 * 64);
    }
}

// -------- GEMM core: s = A.B^T, double-buffered LDS, counted vmcnt ----------
// No S materialization, no atomics. 3 passes, each writes a 2 MB coalesced
// partial array; tiny reduce kernels between passes compute alpha/beta.
// MODE 1: per-block row-min of d.  MODE 2: per-block row-sum of exp.
// MODE 3: per-block col-max of (beta - alpha*d).
template <int MODE>
__global__ __launch_bounds__(256, 2)
void kgemm3(const unsigned short* __restrict__ Aptr, const unsigned short* __restrict__ Bptr,
            const float* __restrict__ rowA, const float* __restrict__ rowB,
            float* __restrict__ partial) {
    const int bid = blockIdx.x;
    const int xcd = bid & 7, q = bid >> 3;
    const int b = xcd >> 1;
    const int by = (xcd & 1) * 16 + (q >> 5);
    const int bx = q & 31;
    const int i0 = by * 128, j0 = bx * 128;
    const int tid = threadIdx.x, lane = tid & 63, wave = tid >> 6;
    const int wm = wave >> 1, wn = wave & 1, l15 = lane & 15, quad = lane >> 4;

    __shared__ unsigned short smem[2][16384];   // 2 x (A 128x64 | B 128x64) = 64 KiB

    const unsigned short* gA = Aptr + ((size_t)b * NN + i0) * CC;
    const unsigned short* gB = Bptr + ((size_t)b * NN + j0) * CC;
    const int rl = lane >> 3, pos = lane & 7;
    const int cbx = pos ^ rl;
    const unsigned short* gAl = gA + (size_t)(wave * 32 + rl) * CC + cbx * 8;
    const unsigned short* gBl = gB + (size_t)(wave * 32 + rl) * CC + cbx * 8;

    stage_tile(gAl, gBl, &smem[0][0] + wave * 2048, &smem[0][8192] + wave * 2048);

    const int ibase = i0 + wm * 64, jbase = j0 + wn * 64;
    (void)jbase;

    float areg[4][4], breg[4][4];
    if (MODE >= 2) {
        #pragma unroll
        for (int ms = 0; ms < 4; ++ms)
            #pragma unroll
            for (int r = 0; r < 4; ++r) {
                int i = b * NN + ibase + ms * 16 + quad * 4 + r;
                areg[ms][r] = rowA[i];
                if (MODE == 3) breg[ms][r] = rowB[i];
            }
    }

    floatx4 acc[4][4];
    #pragma unroll
    for (int ms = 0; ms < 4; ++ms)
        #pragma unroll
        for (int ns = 0; ns < 4; ++ns) acc[ms][ns] = (floatx4){0.f, 0.f, 0.f, 0.f};

    // T3-minimum pipeline: stage(t+1) issued before compute(t); counted vmcnt
    // keeps the prefetch in flight across the barriers (never drain mid-loop).
    #pragma unroll
    for (int t = 0; t < 4; ++t) {
        asm volatile("" ::: "memory");
        __builtin_amdgcn_s_barrier();           // all waves done reading buf[(t+1)&1]
        asm volatile("" ::: "memory");
        if (t < 3)
            stage_tile(gAl + (t + 1) * 64, gBl + (t + 1) * 64,
                       &smem[(t + 1) & 1][0] + wave * 2048,
                       &smem[(t + 1) & 1][8192] + wave * 2048);
        if (t < 3) asm volatile("s_waitcnt vmcnt(8)" ::: "memory");  // stage(t) landed
        else       asm volatile("s_waitcnt vmcnt(0)" ::: "memory");
        __builtin_amdgcn_s_barrier();           // every wave's stage(t) complete
        asm volatile("" ::: "memory");
        const unsigned short* As = smem[t & 1];
        const unsigned short* Bs = As + 8192;
        #pragma unroll
        for (int kk = 0; kk < 64; kk += 32) {
            short8 af[4], bf[4];
            int sw = (quad + (kk >> 3)) ^ (l15 & 7);
            #pragma unroll
            for (int s = 0; s < 4; ++s) {
                af[s] = *(const short8*)&As[(wm * 64 + s * 16 + l15) * 64 + (sw << 3)];
                bf[s] = *(const short8*)&Bs[(wn * 64 + s * 16 + l15) * 64 + (sw << 3)];
            }
            #pragma unroll
            for (int ms = 0; ms < 4; ++ms)
                #pragma unroll
                for (int ns = 0; ns < 4; ++ns)
                    acc[ms][ns] = __builtin_amdgcn_mfma_f32_16x16x32_bf16(af[ms], bf[ns], acc[ms][ns], 0, 0, 0);
        }
    }

    // ---- epilogue: LDS cross-wave reduce -> one coalesced partial store ----
    float* redS = (float*)&smem[0][0];   // aliases buffer 0 (dead after t=2)

    if (MODE == 1) {
        #pragma unroll
        for (int ms = 0; ms < 4; ++ms)
            #pragma unroll
            for (int r = 0; r < 4; ++r) {
                float m = 1e30f;
                #pragma unroll
                for (int ns = 0; ns < 4; ++ns) m = fminf(m, 1.0f - acc[ms][ns][r]);
                m = fminf(m, __shfl_xor(m, 1)); m = fminf(m, __shfl_xor(m, 2));
                m = fminf(m, __shfl_xor(m, 4)); m = fminf(m, __shfl_xor(m, 8));
                if (l15 == 0) redS[(wm * 64 + ms * 16 + quad * 4 + r) * 2 + wn] = m;
            }
        __syncthreads();
        if (tid < 128) {
            float v = fminf(redS[tid * 2], redS[tid * 2 + 1]);
            partial[((size_t)(b * 32 + bx)) * NN + i0 + tid] = v;
        }
    } else if (MODE == 2) {
        #pragma unroll
        for (int ms = 0; ms < 4; ++ms)
            #pragma unroll
            for (int r = 0; r < 4; ++r) {
                float a = areg[ms][r];
                float s = 0.f;
                #pragma unroll
                for (int ns = 0; ns < 4; ++ns) s += __expf(10.0f - a * (1.0f - acc[ms][ns][r]));
                s += __shfl_xor(s, 1); s += __shfl_xor(s, 2);
                s += __shfl_xor(s, 4); s += __shfl_xor(s, 8);
                if (l15 == 0) redS[(wm * 64 + ms * 16 + quad * 4 + r) * 2 + wn] = s;
            }
        __syncthreads();
        if (tid < 128) {
            float v = redS[tid * 2] + redS[tid * 2 + 1];
            partial[((size_t)(b * 32 + bx)) * NN + i0 + tid] = v;
        }
    } else {  // MODE 3
        float cm[4] = {-1e30f, -1e30f, -1e30f, -1e30f};
        #pragma unroll
        for (int ms = 0; ms < 4; ++ms)
            #pragma unroll
            for (int r = 0; r < 4; ++r) {
                float a = areg[ms][r], bl = breg[ms][r];
                #pragma unroll
                for (int ns = 0; ns < 4; ++ns) {
                    float t_ = bl - a * (1.0f - acc[ms][ns][r]);
                    cm[ns] = fmaxf(cm[ns], t_);
                }
            }
        #pragma unroll
        for (int ns = 0; ns < 4; ++ns) {
            float v = cm[ns];
            v = fmaxf(v, __shfl_xor(v, 16)); v = fmaxf(v, __shfl_xor(v, 32));
            if (quad == 0) redS[(wm * 2 + wn) * 64 + ns * 16 + l15] = v;
        }
        __syncthreads();
        if (tid < 128) {
            int wnv = tid >> 6, jl = tid & 63;
            float v = fmaxf(redS[(0 * 2 + wnv) * 64 + jl], redS[(1 * 2 + wnv) * 64 + jl]);
            partial[((size_t)(b * 32 + by)) * NN + j0 + tid] = v;
        }
    }
}

// ---- reduce partial row-min over 32 j-tiles -> alpha -----------------------
__global__ void kredA(const float* __restrict__ partial, float* __restrict__ rowA) {
    int idx = blockIdx.x * 256 + threadIdx.x;      // over BB*NN
    int b = idx >> 12, i = idx & (NN - 1);
    float m = 1e30f;
    #pragma unroll 4
    for (int p = 0; p < 32; ++p) m = fminf(m, partial[((size_t)(b * 32 + p)) * NN + i]);
    rowA[idx] = 10.0f / (m + EPS_MIN);
}

// ---- reduce partial row-sum over 32 j-tiles -> beta ------------------------
__global__ void kredB(const float* __restrict__ partial, float* __restrict__ rowB) {
    int idx = blockIdx.x * 256 + threadIdx.x;
    int b = idx >> 12, i = idx & (NN - 1);
    float s = 0.f;
    #pragma unroll 4
    for (int p = 0; p < 32; ++p) s += partial[((size_t)(b * 32 + p)) * NN + i];
    rowB[idx] = 10.0f - __logf(s);
}

// ---- reduce partial col-max over 32 i-tiles -> exp -> sum ------------------
__global__ void kredC(const float* __restrict__ partial, float* __restrict__ sums) {
    int b = blockIdx.y;
    int j = blockIdx.x * 256 + threadIdx.x;
    float m = -1e30f;
    #pragma unroll 4
    for (int p = 0; p < 32; ++p) m = fmaxf(m, partial[((size_t)(b * 32 + p)) * NN + j]);
    float e = __expf(m);
    __shared__ float red[256];
    red[threadIdx.x] = e; __syncthreads();
    for (int st = 128; st > 0; st >>= 1) {
        if (threadIdx.x < st) red[threadIdx.x] += red[threadIdx.x + st];
        __syncthreads();
    }
    if (threadIdx.x == 0) atomicAdd(&sums[b], red[0]);
}

__global__ void kfinal2(const float* __restrict__ sums, float* __restrict__ out) {
    int t = threadIdx.x;
    if (t < BB) out[t] = logf((float)NN) - logf(sums[t]);
}

extern "C" void kernel_launch(void* const* d_in, const int* in_sizes, int n_in,
                              void* d_out, int out_size, void* d_ws, size_t ws_size,
                              hipStream_t stream) {
    const float* X = (const float*)d_in[0];
    const float* Y = (const float*)d_in[1];
    float* out = (float*)d_out;

    char* w = (char*)d_ws;
    float* ymean        = (float*)(w + 0);                  //   4 KiB
    float* sums         = (float*)(w + 4096);               //  tiny
    float* rowA         = (float*)(w + 8192);               //  64 KiB
    float* rowB         = (float*)(w + 73728);              //  64 KiB
    float* partial      = (float*)(w + 139264);             //   2 MiB
    unsigned short* XnT = (unsigned short*)(w + 2236416);   //   8 MiB
    unsigned short* YnT = (unsigned short*)(w + 10625024);  //   8 MiB (total ~18.2 MiB)

    kmean<<<dim3(BB * CC), 256, 0, stream>>>(Y, ymean, sums);
    kfuse<<<dim3(NN / 64, BB * 2), 256, 0, stream>>>(X, Y, ymean, XnT, YnT);

    dim3 ggrid(8 * 16 * 32);   // 4096 blocks, XCD-partitioned decode in-kernel
    kgemm3<1><<<ggrid, 256, 0, stream>>>(XnT, YnT, rowA, rowB, partial);
    kredA<<<dim3(BB * NN / 256), 256, 0, stream>>>(partial, rowA);
    kgemm3<2><<<ggrid, 256, 0, stream>>>(XnT, YnT, rowA, rowB, partial);
    kredB<<<dim3(BB * NN / 256), 256, 0, stream>>>(partial, rowB);
    kgemm3<3><<<ggrid, 256, 0, stream>>>(XnT, YnT, rowA, rowB, partial);
    kredC<<<dim3(NN / 256, BB), 256, 0, stream>>>(partial, sums);
    kfinal2<<<dim3(1), 64, 0, stream>>>(sums, out);
}

// Round 4
// 200.012 us; speedup vs baseline: 1.5427x; 1.2518x over previous
//
#include <hip/hip_runtime.h>
#include <hip/hip_fp16.h>
#include <cstdint>
#include <cstddef>

#define BB 4
#define CC 256
#define NN 4096
#define EPS_NORM 2.220446049250313e-16f
#define EPS_MIN 1e-5f

typedef __attribute__((ext_vector_type(8))) short short8;
typedef __attribute__((ext_vector_type(4))) float floatx4;

__device__ __forceinline__ unsigned short f2bf(float f) {
    unsigned u = __float_as_uint(f);
    u += 0x7FFFu + ((u >> 16) & 1u);   // RNE
    return (unsigned short)(u >> 16);
}
__device__ __forceinline__ void async_cp16(const void* g, void* l) {
    __builtin_amdgcn_global_load_lds(
        (const __attribute__((address_space(1))) unsigned int*)g,
        (__attribute__((address_space(3))) unsigned int*)l, 16, 0, 0);
}

// ---- K1: per-channel spatial mean of Y (float4); also zero sums ------------
__global__ void kmean(const float* __restrict__ Y, float* __restrict__ ymean,
                      float* __restrict__ sums) {
    if (blockIdx.x == 0 && threadIdx.x < BB) sums[threadIdx.x] = 0.f;
    int bc = blockIdx.x;  // b*CC + c
    const float4* p = (const float4*)(Y + (size_t)bc * NN);
    float s = 0.f;
    for (int k = threadIdx.x; k < NN / 4; k += 256) {
        float4 v = p[k];
        s += (v.x + v.y) + (v.z + v.w);
    }
    __shared__ float red[256];
    red[threadIdx.x] = s; __syncthreads();
    for (int st = 128; st > 0; st >>= 1) {
        if (threadIdx.x < st) red[threadIdx.x] += red[threadIdx.x + st];
        __syncthreads();
    }
    if (threadIdx.x == 0) ymean[bc] = red[0] * (1.0f / NN);
}

// ------- K2: fused norm + normalize + transpose -> bf16 [B,N,C] -------------
__global__ __launch_bounds__(256)
void kfuse(const float* __restrict__ X, const float* __restrict__ Y,
           const float* __restrict__ ymean,
           unsigned short* __restrict__ XnT, unsigned short* __restrict__ YnT) {
    int b = blockIdx.y >> 1, which = blockIdx.y & 1;
    const float* src = which ? Y : X;
    unsigned short* dst = which ? YnT : XnT;
    int n0 = blockIdx.x * 64;
    int tx = threadIdx.x & 63, ty = threadIdx.x >> 6;
    __shared__ float mean_s[CC];
    __shared__ float red[4][64];
    __shared__ float invn[64];
    __shared__ float tile[64][65];
    mean_s[threadIdx.x] = ymean[b * CC + threadIdx.x];
    __syncthreads();
    float vreg[64];
    float s = 0.f;
    #pragma unroll
    for (int k = 0; k < 64; ++k) {
        int c = ty + 4 * k;
        float v = src[(((size_t)b * CC + c) << 12) + n0 + tx] - mean_s[c];
        vreg[k] = v;
        s += v * v;
    }
    red[ty][tx] = s; __syncthreads();
    if (ty == 0) {
        float t = red[0][tx] + red[1][tx] + red[2][tx] + red[3][tx];
        invn[tx] = 1.0f / (sqrtf(t) + EPS_NORM);
    }
    __syncthreads();
    float inv = invn[tx];
    for (int cb = 0; cb < 4; ++cb) {
        if (cb) __syncthreads();
        #pragma unroll
        for (int kk = 0; kk < 16; ++kk) {
            tile[4 * kk + ty][tx] = vreg[cb * 16 + kk] * inv;
        }
        __syncthreads();
        #pragma unroll
        for (int it = 0; it < 16; ++it) {
            int nl = ty + it * 4;
            dst[((size_t)(b * NN + n0 + nl)) * CC + cb * 64 + tx] = f2bf(tile[tx][nl]);
        }
    }
}

// -------- krow: row-panel GEMM, A persistent in LDS, B streamed -------------
// Block = 512 thr (8 waves, 2x4), owns i-panel 128 rows x j-half 2048 cols.
// A [4kc][128][64] persistent (64 KiB); B dbuf [2][256][64] (64 KiB);
// 8 j-tiles x 4 k-steps = 32 pipelined steps, counted vmcnt(4).
// MODE 1: row-min of d -> partial. MODE 2: row-sum of exp -> partial.
// MODE 3: col-max of (beta - alpha*d) -> colpart.
template <int MODE>
__global__ __launch_bounds__(512, 2)
void krow(const unsigned short* __restrict__ Aptr, const unsigned short* __restrict__ Bptr,
          const float* __restrict__ rowA, const float* __restrict__ rowB,
          float* __restrict__ partial, float* __restrict__ colpart) {
    const int bid = blockIdx.x;
    const int b = (bid >> 1) & 3;       // xcd = bid&7 = 2b + jh  -> batch pinned to 2 XCDs
    const int jh = bid & 1;
    const int ip = bid >> 3;            // 0..31
    const int i0 = ip * 128, j0 = jh * 2048;
    const int tid = threadIdx.x, lane = tid & 63, wave = tid >> 6;
    const int wm = wave >> 2, wn = wave & 3, l15 = lane & 15, quad = lane >> 4;

    __shared__ unsigned short As[4 * 128 * 64];    // 64 KiB, [kc][row][64]
    __shared__ unsigned short Bs[2 * 256 * 64];    // 64 KiB, [buf][row][64]
    __shared__ float scratch[4096];                // 16 KiB

    // ---- per-row alpha/beta broadcast loads (issued first: oldest in vmcnt queue)
    float areg[4][4], breg[4][4];
    if (MODE >= 2) {
        #pragma unroll
        for (int ms = 0; ms < 4; ++ms)
            #pragma unroll
            for (int r = 0; r < 4; ++r) {
                int i = b * NN + i0 + wm * 64 + ms * 16 + quad * 4 + r;
                areg[ms][r] = rowA[i];
                if (MODE == 3) breg[ms][r] = rowB[i];
            }
    }

    const int rl = lane >> 3, pos = lane & 7, cbx = pos ^ rl;

    // ---- stage A once: wave w stages kc=w>>1, row-half (w&1)*64, 8 segs ----
    {
        const int kcA = wave >> 1, half = (wave & 1) * 64;
        const unsigned short* gAl = Aptr + ((size_t)b * NN + i0 + half + rl) * CC + kcA * 64 + cbx * 8;
        unsigned short* lA = As + kcA * 8192 + half * 64;
        #pragma unroll
        for (int seg = 0; seg < 8; ++seg)
            async_cp16(gAl + (size_t)seg * 8 * CC, lA + seg * 8 * 64);
    }

    // ---- B staging: 256 rows/step, wave w rows w*32.., 4 segs --------------
    const unsigned short* gBl = Bptr + ((size_t)b * NN + j0 + wave * 32 + rl) * CC + cbx * 8;
    unsigned short* lBw = Bs + wave * 32 * 64;
#define STAGE_B(njt, nkc, p) do { \
        const unsigned short* gs_ = gBl + (size_t)(njt) * 256 * CC + (nkc) * 64; \
        unsigned short* lb_ = lBw + (p) * 16384; \
        async_cp16(gs_ + (size_t)0 * 8 * CC, lb_ + 0 * 8 * 64); \
        async_cp16(gs_ + (size_t)1 * 8 * CC, lb_ + 1 * 8 * 64); \
        async_cp16(gs_ + (size_t)2 * 8 * CC, lb_ + 2 * 8 * 64); \
        async_cp16(gs_ + (size_t)3 * 8 * CC, lb_ + 3 * 8 * 64); \
    } while (0)

    STAGE_B(0, 0, 0);

    floatx4 acc[4][4];
    #pragma unroll
    for (int ms = 0; ms < 4; ++ms)
        #pragma unroll
        for (int ns = 0; ns < 4; ++ns) acc[ms][ns] = (floatx4){0.f, 0.f, 0.f, 0.f};
    float rm[4][4];
    #pragma unroll
    for (int ms = 0; ms < 4; ++ms)
        #pragma unroll
        for (int r = 0; r < 4; ++r) rm[ms][r] = (MODE == 1) ? 1e30f : 0.f;

    for (int jt = 0; jt < 8; ++jt) {
        #pragma unroll
        for (int kc = 0; kc < 4; ++kc) {
            const int p = kc & 1;
            asm volatile("" ::: "memory");
            __builtin_amdgcn_s_barrier();      // all waves done computing buf p^1
            asm volatile("" ::: "memory");
            if (!(jt == 7 && kc == 3)) {
                const int njt = (kc == 3) ? jt + 1 : jt;
                STAGE_B(njt, (kc + 1) & 3, p ^ 1);
                asm volatile("s_waitcnt vmcnt(4)" ::: "memory");   // stage(u) landed
            } else {
                asm volatile("s_waitcnt vmcnt(0)" ::: "memory");
            }
            __builtin_amdgcn_s_barrier();      // every wave's stage(u) complete
            asm volatile("" ::: "memory");
            #pragma unroll
            for (int kk = 0; kk < 64; kk += 32) {
                short8 af[4], bf[4];
                const int sw = (((quad + (kk >> 3)) ^ (l15 & 7)) << 3);
                #pragma unroll
                for (int s = 0; s < 4; ++s) {
                    af[s] = *(const short8*)&As[kc * 8192 + (wm * 64 + s * 16 + l15) * 64 + sw];
                    bf[s] = *(const short8*)&Bs[p * 16384 + (wn * 64 + s * 16 + l15) * 64 + sw];
                }
                #pragma unroll
                for (int ms = 0; ms < 4; ++ms)
                    #pragma unroll
                    for (int ns = 0; ns < 4; ++ns)
                        acc[ms][ns] = __builtin_amdgcn_mfma_f32_16x16x32_bf16(af[ms], bf[ns], acc[ms][ns], 0, 0, 0);
            }
            if (kc == 3) {   // fold finished j-tile into running registers
                if (MODE == 1) {
                    #pragma unroll
                    for (int ms = 0; ms < 4; ++ms)
                        #pragma unroll
                        for (int r = 0; r < 4; ++r) {
                            float m = 1.0f - acc[ms][0][r];
                            #pragma unroll
                            for (int ns = 1; ns < 4; ++ns) m = fminf(m, 1.0f - acc[ms][ns][r]);
                            rm[ms][r] = fminf(rm[ms][r], m);
                        }
                } else if (MODE == 2) {
                    #pragma unroll
                    for (int ms = 0; ms < 4; ++ms)
                        #pragma unroll
                        for (int r = 0; r < 4; ++r) {
                            float a = areg[ms][r];
                            float s = 0.f;
                            #pragma unroll
                            for (int ns = 0; ns < 4; ++ns)
                                s += __expf(10.0f - a * (1.0f - acc[ms][ns][r]));
                            rm[ms][r] += s;
                        }
                } else {
                    #pragma unroll
                    for (int ns = 0; ns < 4; ++ns) {
                        float v = -1e30f;
                        #pragma unroll
                        for (int ms = 0; ms < 4; ++ms)
                            #pragma unroll
                            for (int r = 0; r < 4; ++r)
                                v = fmaxf(v, breg[ms][r] - areg[ms][r] * (1.0f - acc[ms][ns][r]));
                        v = fmaxf(v, __shfl_xor(v, 16));
                        v = fmaxf(v, __shfl_xor(v, 32));
                        if (quad == 0)
                            scratch[((wm * 4 + wn) * 8 + jt) * 64 + ns * 16 + l15] = v;
                    }
                }
                #pragma unroll
                for (int ms = 0; ms < 4; ++ms)
                    #pragma unroll
                    for (int ns = 0; ns < 4; ++ns) acc[ms][ns] = (floatx4){0.f, 0.f, 0.f, 0.f};
            }
        }
    }
#undef STAGE_B

    // ---- block epilogue ----------------------------------------------------
    if (MODE <= 2) {
        #pragma unroll
        for (int ms = 0; ms < 4; ++ms)
            #pragma unroll
            for (int r = 0; r < 4; ++r) {
                float v = rm[ms][r];
                if (MODE == 1) {
                    v = fminf(v, __shfl_xor(v, 1)); v = fminf(v, __shfl_xor(v, 2));
                    v = fminf(v, __shfl_xor(v, 4)); v = fminf(v, __shfl_xor(v, 8));
                } else {
                    v += __shfl_xor(v, 1); v += __shfl_xor(v, 2);
                    v += __shfl_xor(v, 4); v += __shfl_xor(v, 8);
                }
                if (l15 == 0)
                    scratch[(wm * 64 + ms * 16 + quad * 4 + r) * 4 + wn] = v;
            }
        __syncthreads();
        if (tid < 128) {
            float4 q4 = *(const float4*)&scratch[tid * 4];
            float v = (MODE == 1) ? fminf(fminf(q4.x, q4.y), fminf(q4.z, q4.w))
                                  : (q4.x + q4.y) + (q4.z + q4.w);
            partial[((size_t)(b * 2 + jh)) * NN + i0 + tid] = v;
        }
    } else {
        __syncthreads();
        #pragma unroll
        for (int it = 0; it < 4; ++it) {
            int idx = it * 512 + tid;               // 2048 cols
            int jt = idx >> 8, c = idx & 255;
            int wnv = c >> 6, cl = c & 63;
            float v = fmaxf(scratch[((0 * 4 + wnv) * 8 + jt) * 64 + cl],
                            scratch[((1 * 4 + wnv) * 8 + jt) * 64 + cl]);
            colpart[((size_t)(b * 32 + ip)) * NN + j0 + idx] = v;
        }
    }
}

// ---- reduce partial row-min over 2 j-halves -> alpha -----------------------
__global__ void kredA(const float* __restrict__ partial, float* __restrict__ rowA) {
    int idx = blockIdx.x * 256 + threadIdx.x;      // over BB*NN
    int b = idx >> 12, i = idx & (NN - 1);
    float m = fminf(partial[((size_t)(b * 2)) * NN + i],
                    partial[((size_t)(b * 2 + 1)) * NN + i]);
    rowA[idx] = 10.0f / (m + EPS_MIN);
}

// ---- reduce partial row-sum over 2 j-halves -> beta ------------------------
__global__ void kredB(const float* __restrict__ partial, float* __restrict__ rowB) {
    int idx = blockIdx.x * 256 + threadIdx.x;
    int b = idx >> 12, i = idx & (NN - 1);
    float s = partial[((size_t)(b * 2)) * NN + i] +
              partial[((size_t)(b * 2 + 1)) * NN + i];
    rowB[idx] = 10.0f - __logf(s);
}

// ---- reduce colpart over 32 i-panels -> exp -> sum per batch ---------------
__global__ void kredC(const float* __restrict__ colpart, float* __restrict__ sums) {
    int b = blockIdx.y;
    int j = blockIdx.x * 256 + threadIdx.x;
    float m = -1e30f;
    #pragma unroll 4
    for (int p = 0; p < 32; ++p)
        m = fmaxf(m, colpart[((size_t)(b * 32 + p)) * NN + j]);
    float e = __expf(m);
    __shared__ float red[256];
    red[threadIdx.x] = e; __syncthreads();
    for (int st = 128; st > 0; st >>= 1) {
        if (threadIdx.x < st) red[threadIdx.x] += red[threadIdx.x + st];
        __syncthreads();
    }
    if (threadIdx.x == 0) atomicAdd(&sums[b], red[0]);
}

__global__ void kfinal2(const float* __restrict__ sums, float* __restrict__ out) {
    int t = threadIdx.x;
    if (t < BB) out[t] = logf((float)NN) - logf(sums[t]);
}

extern "C" void kernel_launch(void* const* d_in, const int* in_sizes, int n_in,
                              void* d_out, int out_size, void* d_ws, size_t ws_size,
                              hipStream_t stream) {
    const float* X = (const float*)d_in[0];
    const float* Y = (const float*)d_in[1];
    float* out = (float*)d_out;

    char* w = (char*)d_ws;
    float* ymean        = (float*)(w + 0);                  //   4 KiB
    float* sums         = (float*)(w + 4096);               //  tiny
    float* rowA         = (float*)(w + 8192);               //  64 KiB
    float* rowB         = (float*)(w + 73728);              //  64 KiB
    float* partial      = (float*)(w + 139264);             // 128 KiB
    float* colpart      = (float*)(w + 270336);             //   2 MiB
    unsigned short* XnT = (unsigned short*)(w + 2367488);   //   8 MiB
    unsigned short* YnT = (unsigned short*)(w + 10756096);  //   8 MiB (total ~18.3 MiB)

    kmean<<<dim3(BB * CC), 256, 0, stream>>>(Y, ymean, sums);
    kfuse<<<dim3(NN / 64, BB * 2), 256, 0, stream>>>(X, Y, ymean, XnT, YnT);

    dim3 ggrid(256);   // 4b x 32ip x 2jh, XCD-pinned decode in-kernel
    krow<1><<<ggrid, 512, 0, stream>>>(XnT, YnT, rowA, rowB, partial, colpart);
    kredA<<<dim3(BB * NN / 256), 256, 0, stream>>>(partial, rowA);
    krow<2><<<ggrid, 512, 0, stream>>>(XnT, YnT, rowA, rowB, partial, colpart);
    kredB<<<dim3(BB * NN / 256), 256, 0, stream>>>(partial, rowB);
    krow<3><<<ggrid, 512, 0, stream>>>(XnT, YnT, rowA, rowB, partial, colpart);
    kredC<<<dim3(NN / 256, BB), 256, 0, stream>>>(colpart, sums);
    kfinal2<<<dim3(1), 64, 0, stream>>>(sums, out);
}